// Round 14
// baseline (145.957 us; speedup 1.0000x reference)
//
#include <hip/hip_runtime.h>

// Problem constants
#define BATCH 8
#define SEQ   512
#define EMB   1024
#define NH    16
#define HD    64
// dist table rows = 2*512-1 = 1023 (+1 zero pad row)

typedef __bf16 bf16x8 __attribute__((ext_vector_type(8)));
typedef float  f32x4  __attribute__((ext_vector_type(4)));

__device__ __forceinline__ unsigned short f2bf(float f){
  union { float f; unsigned u; } v; v.f = f;
  unsigned r = v.u + 0x7FFFu + ((v.u >> 16) & 1u);
  return (unsigned short)(r >> 16);
}
__device__ __forceinline__ unsigned short f2bfr(float f){ // cheap round
  union { float f; unsigned u; } v; v.f = f;
  return (unsigned short)((v.u + 0x8000u) >> 16);
}
__device__ __forceinline__ float bf2f(unsigned short s){
  union { unsigned u; float f; } v; v.u = ((unsigned)s) << 16;
  return v.f;
}

// 16-lane (DPP row) butterfly reductions -- pure VALU pipe, no LDS traffic.
__device__ __forceinline__ float dpp_max16(float x){
  int t;
  t = __builtin_amdgcn_update_dpp(0, __builtin_bit_cast(int, x), 0xB1, 0xF, 0xF, true);
  x = fmaxf(x, __builtin_bit_cast(float, t));
  t = __builtin_amdgcn_update_dpp(0, __builtin_bit_cast(int, x), 0x4E, 0xF, 0xF, true);
  x = fmaxf(x, __builtin_bit_cast(float, t));
  t = __builtin_amdgcn_update_dpp(0, __builtin_bit_cast(int, x), 0x141, 0xF, 0xF, true);
  x = fmaxf(x, __builtin_bit_cast(float, t));
  t = __builtin_amdgcn_update_dpp(0, __builtin_bit_cast(int, x), 0x140, 0xF, 0xF, true);
  x = fmaxf(x, __builtin_bit_cast(float, t));
  return x;
}
__device__ __forceinline__ float dpp_sum16(float x){
  int t;
  t = __builtin_amdgcn_update_dpp(0, __builtin_bit_cast(int, x), 0xB1, 0xF, 0xF, true);
  x += __builtin_bit_cast(float, t);
  t = __builtin_amdgcn_update_dpp(0, __builtin_bit_cast(int, x), 0x4E, 0xF, 0xF, true);
  x += __builtin_bit_cast(float, t);
  t = __builtin_amdgcn_update_dpp(0, __builtin_bit_cast(int, x), 0x141, 0xF, 0xF, true);
  x += __builtin_bit_cast(float, t);
  t = __builtin_amdgcn_update_dpp(0, __builtin_bit_cast(int, x), 0x140, 0xF, 0xF, true);
  x += __builtin_bit_cast(float, t);
  return x;
}

// XOR-swizzle helpers for LDS tiles with rows of 64 bf16 (128 B rows).
__device__ __forceinline__ int swzc(int row, int chunk){
  return row * 128 + (((chunk ^ (row & 7)) & 7) << 4);
}
__device__ __forceinline__ int swz2(int row, int col){ // col = bf16 element 0..63
  return row * 128 + ((((col >> 3) ^ (row & 7)) & 7) << 4) + ((col & 7) << 1);
}

// async global->LDS, 16B per lane, linear dest (wave-uniform base + lane*16)
__device__ __forceinline__ void gload16(const unsigned short* g, unsigned char* lds){
  __builtin_amdgcn_global_load_lds((const __attribute__((address_space(1))) unsigned int*)g,
                                   (__attribute__((address_space(3))) unsigned int*)lds,
                                   16, 0, 0);
}

// ---------------- prep (one dispatch): hidden->bf16 | dist->bf16 | 3 weight transposes ----------------
// blocks 0..4095: hidden; 4096..4351: dist; 4352..7423: wt (1024 per z)
__global__ void k_pre(const float* __restrict__ hid, unsigned short* __restrict__ hidb,
                      const float* __restrict__ dist, unsigned short* __restrict__ distb,
                      const float* __restrict__ Wq, const float* __restrict__ Wk,
                      const float* __restrict__ Wv, unsigned short* __restrict__ wqt,
                      unsigned short* __restrict__ wkt, unsigned short* __restrict__ wvt){
  int bid = blockIdx.x;
  int t = threadIdx.x;
  if (bid < 4096){
    int i = (bid * 256 + t) * 4;
    float4 v = *(const float4*)(hid + i);
    ushort4 o; o.x = f2bf(v.x); o.y = f2bf(v.y); o.z = f2bf(v.z); o.w = f2bf(v.w);
    *(ushort4*)(hidb + i) = o;
  } else if (bid < 4352){
    int i = (bid - 4096) * 256 + t;                // 65536 total
    distb[i] = (i < 1023 * 64) ? f2bf(dist[i]) : (unsigned short)0;
  } else {
    int wt = bid - 4352;
    int z = wt >> 10, rem = wt & 1023;
    const float* W = (z == 0) ? Wq : (z == 1) ? Wk : Wv;
    unsigned short* WT = (z == 0) ? wqt : (z == 1) ? wkt : wvt;
    __shared__ float tl[32][33];
    int n0 = (rem & 31) * 32, k0 = (rem >> 5) * 32;
    int tx = t & 31, ty = t >> 5;
#pragma unroll
    for (int i = 0; i < 4; i++)
      tl[ty + 8*i][tx] = W[(k0 + ty + 8*i) * EMB + n0 + tx];
    __syncthreads();
#pragma unroll
    for (int i = 0; i < 4; i++)
      WT[(n0 + ty + 8*i) * EMB + k0 + tx] = f2bf(tl[tx][ty + 8*i]);
  }
}

// ---------------- fused QKV projection GEMM (blockIdx.z = which) ----------------
// XCD-aware tile swizzle within each z-plane: XCD c owns 32 tiles = 4 A-panels
// x all 8 B-column tiles -> per-XCD L2 working set = 1MB A + 2MB B <= 4MB.
__global__ __launch_bounds__(256, 3) void k_gemm3(const unsigned short* __restrict__ A,
                                                  const unsigned short* __restrict__ wqt,
                                                  const unsigned short* __restrict__ wkt,
                                                  const unsigned short* __restrict__ wvt,
                                                  const float* __restrict__ bq,
                                                  const float* __restrict__ bk,
                                                  const float* __restrict__ bv,
                                                  unsigned short* __restrict__ qb,
                                                  unsigned short* __restrict__ kb,
                                                  unsigned short* __restrict__ vtb){
  int z = blockIdx.z;
  const unsigned short* BT = (z == 0) ? wqt : (z == 1) ? wkt : wvt;
  const float* bias = (z == 0) ? bq : (z == 1) ? bk : bv;
  unsigned short* out = (z == 0) ? qb : (z == 1) ? kb : vtb;
  int mode = (z == 2);

  __shared__ __align__(16) unsigned char sA[128 * 128];
  __shared__ __align__(16) unsigned char sB[128 * 128];
  int id2 = blockIdx.x + 8 * blockIdx.y;             // 0..255 within z-plane
  int s2  = (id2 & 7) * 32 + (id2 >> 3);             // bijective XCD chunking
  int m0 = (s2 >> 3) * 128, n0 = (s2 & 7) * 128;
  int t = threadIdx.x, w = t >> 6, lane = t & 63, g = lane >> 4, lr = lane & 15;
  int rowbase = (w >> 1) * 64, colbase = (w & 1) * 64;
  int lrow = lane >> 3, lc = lane & 7;
  f32x4 acc[4][4] = {};
  for (int k0 = 0; k0 < EMB; k0 += 64){
    __syncthreads();
#pragma unroll
    for (int i = 0; i < 4; i++){
      int row = (w + 4*i) * 8 + lrow;
      int cg  = lc ^ (row & 7);
      gload16(A  + (m0 + row) * EMB + k0 + cg*8, sA + (w + 4*i) * 1024);
      gload16(BT + (n0 + row) * EMB + k0 + cg*8, sB + (w + 4*i) * 1024);
    }
    __syncthreads();
#pragma unroll
    for (int kk = 0; kk < 2; kk++){
      bf16x8 af[4], bfv[4];
#pragma unroll
      for (int i = 0; i < 4; i++) af[i]  = *(const bf16x8*)(sA + swzc(rowbase + 16*i + lr, kk*4 + g));
#pragma unroll
      for (int j = 0; j < 4; j++) bfv[j] = *(const bf16x8*)(sB + swzc(colbase + 16*j + lr, kk*4 + g));
#pragma unroll
      for (int i = 0; i < 4; i++)
#pragma unroll
        for (int j = 0; j < 4; j++)
          acc[i][j] = __builtin_amdgcn_mfma_f32_16x16x32_bf16(af[i], bfv[j], acc[i][j], 0, 0, 0);
    }
  }
#pragma unroll
  for (int i = 0; i < 4; i++)
#pragma unroll
    for (int j = 0; j < 4; j++)
#pragma unroll
      for (int r = 0; r < 4; r++){
        int m = m0 + rowbase + 16*i + 4*g + r;
        int n = n0 + colbase + 16*j + lr;
        float val = acc[i][j][r] + bias[n];
        int b = m >> 9, s = m & 511, h = n >> 6, d = n & 63;
        int idx = (mode == 0) ? (((b*NH + h)*SEQ + s)*HD + d)
                              : (((b*NH + h)*HD + d)*SEQ + s);
        out[idx] = f2bf(val);
      }
}

// ---------------- fused rel-pos attention: BARRIER-FREE ----------------
// grid: 1024 = B*H*(S/64); block 256 = 4 waves x 16 l-rows each.
// NO K/V LDS staging, NO barriers: per head K+V = 128 KB; with the XCD swizzle
// each XCD's K/V set = 2 MB < 4 MB L2. Each wave reads its MFMA K/V fragments
// DIRECTLY from global (L2/L1) as 16 B loads. Waves are fully independent ->
// no barrier convoy; latencies covered by free-running waves. V fragments for
// the PV step are loaded at iteration top (~whole iteration ahead of use).
// Per-wave LDS stripes only (band terms + P, private, same-wave ordering).
// LDS 28.9 KB. DPP softmax; setprio on MFMA clusters.
__global__ __launch_bounds__(256, 2) void k_attn(const unsigned short* __restrict__ qb,
                                                 const unsigned short* __restrict__ kb,
                                                 const unsigned short* __restrict__ vtb,
                                                 const unsigned short* __restrict__ distb,
                                                 const float* __restrict__ mask,
                                                 float* __restrict__ out){
  __shared__ __align__(16) unsigned char sSA[4][2624];      // 64 rows x 40 B + dump@2560
  __shared__ __align__(16) unsigned char sSB[4][2560];      // 64 rows x 40 B
  __shared__ __align__(16) unsigned char sP[4][2048];       // 16 rows x 128 B (swizzled)

  const float SCL  = 0.125f * 1.4426950408889634f;   // /sqrt(64) * log2(e)
  const float L2E  = 1.4426950408889634f;

  int bid = blockIdx.x;
  int wgid = (bid & 7) * 128 + (bid >> 3);           // bijective XCD swizzle (1024 % 8 == 0)
  int lt = wgid & 7, h = (wgid >> 3) & 15, b = wgid >> 7;
  int L0 = lt * 64;
  int bh = b * NH + h;
  int t = threadIdx.x, w = t >> 6, lane = t & 63, g = lane >> 4, lr = lane & 15;
  int lbase = 16 * w;
  unsigned char* mySA = sSA[w];
  unsigned char* mySB = sSB[w];
  unsigned char* myP  = sP[w];
  const float* maskp = mask + b * SEQ;

  // Q fragments hoisted to registers (rows L0+16w+lr)
  const unsigned short* qrow = qb + (bh * SEQ + L0 + lbase + lr) * HD + 8 * g;
  bf16x8 aq0 = *(const bf16x8*)qrow;
  bf16x8 aq1 = *(const bf16x8*)(qrow + 32);

  // PE fragments: 5 tiles jt = w..w+4, 2 k-halves each
  bf16x8 pe[5][2];
#define LOAD_PE(JB) do {                                                     \
    const unsigned short* _pb = distb + ((JB) + 16*w + lr) * HD + 8*g;       \
    _Pragma("unroll")                                                        \
    for (int _j = 0; _j < 5; _j++){                                          \
      pe[_j][0] = *(const bf16x8*)(_pb + _j*16*HD);                          \
      pe[_j][1] = *(const bf16x8*)(_pb + _j*16*HD + 32); }                   \
  } while(0)

  const unsigned short* kbase = kb  + bh * SEQ * HD;
  const unsigned short* vbase = vtb + bh * HD * SEQ;

  LOAD_PE(L0 + 448);

  f32x4 o[4] = {};
  float mrun[4], srun[4];
#pragma unroll
  for (int r = 0; r < 4; r++){ mrun[r] = -1e30f; srun[r] = 0.f; }

  for (int rt = 0; rt < 8; rt++){
    int R0 = rt * 64;
    const unsigned short* kt = kbase + R0 * HD;
    const unsigned short* vt = vbase + R0;

    // V fragments for PV: issue at iteration top (independent; whole
    // iteration of QK/bands/softmax to land from L2)
    bf16x8 vf[2][4];
#pragma unroll
    for (int kk = 0; kk < 2; kk++)
#pragma unroll
      for (int df = 0; df < 4; df++)
        vf[kk][df] = *(const bf16x8*)(vt + (16*df + lr) * SEQ + kk*32 + 8*g);

    // mask values for this r-tile (column rr = 16f+lr)
    float mreg[4];
#pragma unroll
    for (int f = 0; f < 4; f++) mreg[f] = maskp[R0 + 16*f + lr];

    __builtin_amdgcn_s_setprio(1);
    // merged QK + B-band per K-tile f; K fragments direct from global (L2/L1)
    f32x4 sc[4];
#pragma unroll
    for (int f = 0; f < 4; f++){
      bf16x8 k0 = *(const bf16x8*)(kt + (16*f + lr) * HD + 8*g);
      bf16x8 k1 = *(const bf16x8*)(kt + (16*f + lr) * HD + 32 + 8*g);
      f32x4 a = {};
      a = __builtin_amdgcn_mfma_f32_16x16x32_bf16(aq0, k0, a, 0, 0, 0);
      a = __builtin_amdgcn_mfma_f32_16x16x32_bf16(aq1, k1, a, 0, 0, 0);
      sc[f] = a;
      // B-band: i -> K rows 16f.., j -> PE tiles (3-f) and (4-f) relative to wave
      f32x4 b0 = {}, b1 = {};
      b0 = __builtin_amdgcn_mfma_f32_16x16x32_bf16(k0, pe[3 - f][0], b0, 0, 0, 0);
      b0 = __builtin_amdgcn_mfma_f32_16x16x32_bf16(k1, pe[3 - f][1], b0, 0, 0, 0);
      b1 = __builtin_amdgcn_mfma_f32_16x16x32_bf16(k0, pe[4 - f][0], b1, 0, 0, 0);
      b1 = __builtin_amdgcn_mfma_f32_16x16x32_bf16(k1, pe[4 - f][1], b1, 0, 0, 0);
#pragma unroll
      for (int reg = 0; reg < 4; reg++){
        int ss = 4*g + reg + lr;
        float v = (ss >= 15) ? b0[reg] : b1[reg];
        int row = 16*f + 4*g + reg;            // r_kv (block-local)
        int col = (ss + 1) & 15;               // l (wave-local) -- bijection
        *(unsigned short*)(mySB + row*40 + col*2) = f2bfr(v);
      }
    }

    // A-band: i -> q rows (wave-local l), j -> PE rows; store transposed [r_kv][l]
#pragma unroll
    for (int jt2 = 0; jt2 < 5; jt2++){
      f32x4 a = {};
      a = __builtin_amdgcn_mfma_f32_16x16x32_bf16(aq0, pe[jt2][0], a, 0, 0, 0);
      a = __builtin_amdgcn_mfma_f32_16x16x32_bf16(aq1, pe[jt2][1], a, 0, 0, 0);
#pragma unroll
      for (int reg = 0; reg < 4; reg++){
        int rloc = 63 + 4*g + reg - lr - 16*jt2;   // r_kv (block-local), may be OOR
        int addr = ((unsigned)rloc < 64u) ? (rloc*40 + (4*g + reg)*2) : 2560; // dump
        *(unsigned short*)(mySA + addr) = f2bfr(a[reg]);
      }
    }
    __builtin_amdgcn_s_setprio(0);

    // PE prefetch for next iteration (regs dead now; whole rest of iter to land)
    if (rt < 7) LOAD_PE(L0 + 448 - 64*(rt + 1));

    // score combine: qk + SA_T[rr][l] + SB[rr][l], scale, mask (exp2 domain)
#pragma unroll
    for (int f = 0; f < 4; f++){
      ushort4 sa = *(const ushort4*)(mySA + (16*f + lr)*40 + 8*g);
      ushort4 sb = *(const ushort4*)(mySB + (16*f + lr)*40 + 8*g);
      float madd = mreg[f] * L2E;
      sc[f][0] = (sc[f][0] + bf2f(sa.x) + bf2f(sb.x)) * SCL + madd;
      sc[f][1] = (sc[f][1] + bf2f(sa.y) + bf2f(sb.y)) * SCL + madd;
      sc[f][2] = (sc[f][2] + bf2f(sa.z) + bf2f(sb.z)) * SCL + madd;
      sc[f][3] = (sc[f][3] + bf2f(sa.w) + bf2f(sb.w)) * SCL + madd;
    }

    // online softmax (exp2 domain); DPP row reductions (VALU pipe)
    float fac[4];
#pragma unroll
    for (int r = 0; r < 4; r++){
      float tm = fmaxf(fmaxf(sc[0][r], sc[1][r]), fmaxf(sc[2][r], sc[3][r]));
      tm = dpp_max16(tm);
      float mnew = fmaxf(mrun[r], tm);
      float fr = exp2f(mrun[r] - mnew);
      float ps = 0.f;
#pragma unroll
      for (int f = 0; f < 4; f++){ float p = exp2f(sc[f][r] - mnew); sc[f][r] = p; ps += p; }
      ps = dpp_sum16(ps);
      srun[r] = srun[r] * fr + ps;
      mrun[r] = mnew;
      fac[r]  = fr;
    }
#pragma unroll
    for (int df = 0; df < 4; df++)
#pragma unroll
      for (int r = 0; r < 4; r++) o[df][r] *= fac[r];

    // write P (bf16) into this wave's private stripe (same-wave DS ordering)
#pragma unroll
    for (int f = 0; f < 4; f++)
#pragma unroll
      for (int r = 0; r < 4; r++)
        *(unsigned short*)(myP + swz2(4*g + r, 16*f + lr)) = f2bfr(sc[f][r]);

    // PV: O[16 l x 64 d] += P[16 l x 64 r] * V[64 r x 64 d] (V in regs)
    __builtin_amdgcn_s_setprio(1);
#pragma unroll
    for (int kk = 0; kk < 2; kk++){
      bf16x8 pf = *(const bf16x8*)(myP + swzc(lr, kk*4 + g));
#pragma unroll
      for (int df = 0; df < 4; df++)
        o[df] = __builtin_amdgcn_mfma_f32_16x16x32_bf16(pf, vf[kk][df], o[df], 0, 0, 0);
    }
    __builtin_amdgcn_s_setprio(0);
  }

  // epilogue: normalize and write out[b, l, h*64+d] (f32)
#pragma unroll
  for (int r = 0; r < 4; r++){
    float inv = 1.0f / srun[r];
#pragma unroll
    for (int df = 0; df < 4; df++){
      int l = L0 + lbase + 4*g + r;
      out[(b * SEQ + l) * EMB + h * HD + 16*df + lr] = o[df][r] * inv;
    }
  }
#undef LOAD_PE
}

extern "C" void kernel_launch(void* const* d_in, const int* in_sizes, int n_in,
                              void* d_out, int out_size, void* d_ws, size_t ws_size,
                              hipStream_t stream) {
  (void)in_sizes; (void)n_in; (void)out_size; (void)ws_size;
  const float* hid  = (const float*)d_in[0];
  const float* mask = (const float*)d_in[1];
  const float* Wq   = (const float*)d_in[2];
  const float* bq   = (const float*)d_in[3];
  const float* Wk   = (const float*)d_in[4];
  const float* bk   = (const float*)d_in[5];
  const float* Wv   = (const float*)d_in[6];
  const float* bv   = (const float*)d_in[7];
  const float* dist = (const float*)d_in[8];
  float* out = (float*)d_out;

  unsigned char* ws = (unsigned char*)d_ws;
  unsigned short* hidb  = (unsigned short*)ws;                    // 4096*1024 bf16 = 8 MB
  unsigned short* wqt   = hidb + 4096 * 1024;                     // 2 MB each
  unsigned short* wkt   = wqt  + 1024 * 1024;
  unsigned short* wvt   = wkt  + 1024 * 1024;
  unsigned short* distb = wvt  + 1024 * 1024;                     // 1024*64 bf16 (padded)
  unsigned short* qb    = distb + 1024 * 64;                      // [B,H,S,D] bf16, 8 MB
  unsigned short* kb    = qb + BATCH * NH * SEQ * HD;
  unsigned short* vtb   = kb + BATCH * NH * SEQ * HD;             // [B,H,D,S] bf16

  k_pre<<<7424, 256, 0, stream>>>(hid, hidb, dist, distb, Wq, Wk, Wv, wqt, wkt, wvt);
  k_gemm3<<<dim3(8, 32, 3), 256, 0, stream>>>(hidb, wqt, wkt, wvt, bq, bk, bv, qb, kb, vtb);
  k_attn<<<1024, 256, 0, stream>>>(qb, kb, vtb, distb, mask, out);
}

// Round 15
// 103.086 us; speedup vs baseline: 1.4159x; 1.4159x over previous
//
#include <hip/hip_runtime.h>

// Problem constants
#define BATCH 8
#define SEQ   512
#define EMB   1024
#define NH    16
#define HD    64
// dist table rows = 2*512-1 = 1023 (+1 zero pad row)

typedef __bf16 bf16x8 __attribute__((ext_vector_type(8)));
typedef float  f32x4  __attribute__((ext_vector_type(4)));

__device__ __forceinline__ unsigned short f2bf(float f){
  union { float f; unsigned u; } v; v.f = f;
  unsigned r = v.u + 0x7FFFu + ((v.u >> 16) & 1u);
  return (unsigned short)(r >> 16);
}
__device__ __forceinline__ unsigned short f2bfr(float f){ // cheap round
  union { float f; unsigned u; } v; v.f = f;
  return (unsigned short)((v.u + 0x8000u) >> 16);
}
__device__ __forceinline__ float bf2f(unsigned short s){
  union { unsigned u; float f; } v; v.u = ((unsigned)s) << 16;
  return v.f;
}

// 16-lane (DPP row) butterfly reductions -- pure VALU pipe, no LDS traffic.
__device__ __forceinline__ float dpp_max16(float x){
  int t;
  t = __builtin_amdgcn_update_dpp(0, __builtin_bit_cast(int, x), 0xB1, 0xF, 0xF, true);
  x = fmaxf(x, __builtin_bit_cast(float, t));
  t = __builtin_amdgcn_update_dpp(0, __builtin_bit_cast(int, x), 0x4E, 0xF, 0xF, true);
  x = fmaxf(x, __builtin_bit_cast(float, t));
  t = __builtin_amdgcn_update_dpp(0, __builtin_bit_cast(int, x), 0x141, 0xF, 0xF, true);
  x = fmaxf(x, __builtin_bit_cast(float, t));
  t = __builtin_amdgcn_update_dpp(0, __builtin_bit_cast(int, x), 0x140, 0xF, 0xF, true);
  x = fmaxf(x, __builtin_bit_cast(float, t));
  return x;
}
__device__ __forceinline__ float dpp_sum16(float x){
  int t;
  t = __builtin_amdgcn_update_dpp(0, __builtin_bit_cast(int, x), 0xB1, 0xF, 0xF, true);
  x += __builtin_bit_cast(float, t);
  t = __builtin_amdgcn_update_dpp(0, __builtin_bit_cast(int, x), 0x4E, 0xF, 0xF, true);
  x += __builtin_bit_cast(float, t);
  t = __builtin_amdgcn_update_dpp(0, __builtin_bit_cast(int, x), 0x141, 0xF, 0xF, true);
  x += __builtin_bit_cast(float, t);
  t = __builtin_amdgcn_update_dpp(0, __builtin_bit_cast(int, x), 0x140, 0xF, 0xF, true);
  x += __builtin_bit_cast(float, t);
  return x;
}

// XOR-swizzle helpers for LDS tiles with rows of 64 bf16 (128 B rows).
__device__ __forceinline__ int swzc(int row, int chunk){
  return row * 128 + (((chunk ^ (row & 7)) & 7) << 4);
}
__device__ __forceinline__ int swz2(int row, int col){ // col = bf16 element 0..63
  return row * 128 + ((((col >> 3) ^ (row & 7)) & 7) << 4) + ((col & 7) << 1);
}

// async global->LDS, 16B per lane, linear dest (wave-uniform base + lane*16)
__device__ __forceinline__ void gload16(const unsigned short* g, unsigned char* lds){
  __builtin_amdgcn_global_load_lds((const __attribute__((address_space(1))) unsigned int*)g,
                                   (__attribute__((address_space(3))) unsigned int*)lds,
                                   16, 0, 0);
}

// lgkm-only barrier: producer's ds ops visible, but in-flight VMEM (reg-staged
// K/V prefetch, PE loads) stays outstanding across it -- no vmcnt(0) drain.
__device__ __forceinline__ void bar_lds(){
  asm volatile("s_waitcnt lgkmcnt(0)" ::: "memory");
  __builtin_amdgcn_s_barrier();
}

// ---------------- prep (one dispatch): hidden->bf16 | dist->bf16 | 3 weight transposes ----------------
// blocks 0..4095: hidden; 4096..4351: dist; 4352..7423: wt (1024 per z)
__global__ void k_pre(const float* __restrict__ hid, unsigned short* __restrict__ hidb,
                      const float* __restrict__ dist, unsigned short* __restrict__ distb,
                      const float* __restrict__ Wq, const float* __restrict__ Wk,
                      const float* __restrict__ Wv, unsigned short* __restrict__ wqt,
                      unsigned short* __restrict__ wkt, unsigned short* __restrict__ wvt){
  int bid = blockIdx.x;
  int t = threadIdx.x;
  if (bid < 4096){
    int i = (bid * 256 + t) * 4;
    float4 v = *(const float4*)(hid + i);
    ushort4 o; o.x = f2bf(v.x); o.y = f2bf(v.y); o.z = f2bf(v.z); o.w = f2bf(v.w);
    *(ushort4*)(hidb + i) = o;
  } else if (bid < 4352){
    int i = (bid - 4096) * 256 + t;                // 65536 total
    distb[i] = (i < 1023 * 64) ? f2bf(dist[i]) : (unsigned short)0;
  } else {
    int wt = bid - 4352;
    int z = wt >> 10, rem = wt & 1023;
    const float* W = (z == 0) ? Wq : (z == 1) ? Wk : Wv;
    unsigned short* WT = (z == 0) ? wqt : (z == 1) ? wkt : wvt;
    __shared__ float tl[32][33];
    int n0 = (rem & 31) * 32, k0 = (rem >> 5) * 32;
    int tx = t & 31, ty = t >> 5;
#pragma unroll
    for (int i = 0; i < 4; i++)
      tl[ty + 8*i][tx] = W[(k0 + ty + 8*i) * EMB + n0 + tx];
    __syncthreads();
#pragma unroll
    for (int i = 0; i < 4; i++)
      WT[(n0 + ty + 8*i) * EMB + k0 + tx] = f2bf(tl[tx][ty + 8*i]);
  }
}

// ---------------- fused QKV projection GEMM (blockIdx.z = which) ----------------
// XCD-aware tile swizzle within each z-plane: XCD c owns 32 tiles = 4 A-panels
// x all 8 B-column tiles -> per-XCD L2 working set = 1MB A + 2MB B <= 4MB.
__global__ __launch_bounds__(256, 3) void k_gemm3(const unsigned short* __restrict__ A,
                                                  const unsigned short* __restrict__ wqt,
                                                  const unsigned short* __restrict__ wkt,
                                                  const unsigned short* __restrict__ wvt,
                                                  const float* __restrict__ bq,
                                                  const float* __restrict__ bk,
                                                  const float* __restrict__ bv,
                                                  unsigned short* __restrict__ qb,
                                                  unsigned short* __restrict__ kb,
                                                  unsigned short* __restrict__ vtb){
  int z = blockIdx.z;
  const unsigned short* BT = (z == 0) ? wqt : (z == 1) ? wkt : wvt;
  const float* bias = (z == 0) ? bq : (z == 1) ? bk : bv;
  unsigned short* out = (z == 0) ? qb : (z == 1) ? kb : vtb;
  int mode = (z == 2);

  __shared__ __align__(16) unsigned char sA[128 * 128];
  __shared__ __align__(16) unsigned char sB[128 * 128];
  int id2 = blockIdx.x + 8 * blockIdx.y;             // 0..255 within z-plane
  int s2  = (id2 & 7) * 32 + (id2 >> 3);             // bijective XCD chunking
  int m0 = (s2 >> 3) * 128, n0 = (s2 & 7) * 128;
  int t = threadIdx.x, w = t >> 6, lane = t & 63, g = lane >> 4, lr = lane & 15;
  int rowbase = (w >> 1) * 64, colbase = (w & 1) * 64;
  int lrow = lane >> 3, lc = lane & 7;
  f32x4 acc[4][4] = {};
  for (int k0 = 0; k0 < EMB; k0 += 64){
    __syncthreads();
#pragma unroll
    for (int i = 0; i < 4; i++){
      int row = (w + 4*i) * 8 + lrow;
      int cg  = lc ^ (row & 7);
      gload16(A  + (m0 + row) * EMB + k0 + cg*8, sA + (w + 4*i) * 1024);
      gload16(BT + (n0 + row) * EMB + k0 + cg*8, sB + (w + 4*i) * 1024);
    }
    __syncthreads();
#pragma unroll
    for (int kk = 0; kk < 2; kk++){
      bf16x8 af[4], bfv[4];
#pragma unroll
      for (int i = 0; i < 4; i++) af[i]  = *(const bf16x8*)(sA + swzc(rowbase + 16*i + lr, kk*4 + g));
#pragma unroll
      for (int j = 0; j < 4; j++) bfv[j] = *(const bf16x8*)(sB + swzc(colbase + 16*j + lr, kk*4 + g));
#pragma unroll
      for (int i = 0; i < 4; i++)
#pragma unroll
        for (int j = 0; j < 4; j++)
          acc[i][j] = __builtin_amdgcn_mfma_f32_16x16x32_bf16(af[i], bfv[j], acc[i][j], 0, 0, 0);
    }
  }
#pragma unroll
  for (int i = 0; i < 4; i++)
#pragma unroll
    for (int j = 0; j < 4; j++)
#pragma unroll
      for (int r = 0; r < 4; r++){
        int m = m0 + rowbase + 16*i + 4*g + r;
        int n = n0 + colbase + 16*j + lr;
        float val = acc[i][j][r] + bias[n];
        int b = m >> 9, s = m & 511, h = n >> 6, d = n & 63;
        int idx = (mode == 0) ? (((b*NH + h)*SEQ + s)*HD + d)
                              : (((b*NH + h)*HD + d)*SEQ + s);
        out[idx] = f2bf(val);
      }
}

// ---------------- fused rel-pos attention (champion config, r7/r12 bench) ----------------
// grid: 1024 = B*H*(S/64); block 256 = 4 waves x 16 l-rows each.
// K/V SINGLE-buffered in LDS (37.4 KB); next tile staged in REGISTERS (loads
// issued one iteration early); per-iter: bar1 -> commit staged tile ->
// issue next loads -> bar2 -> compute. Barriers are lgkm-only, so staged
// K/V + PE global loads stay in flight across them (no vmcnt(0) drain).
// Per-wave private band stripes (bf16, 40 B rows); P overlays SA.
// Bijective XCD swizzle; DPP softmax reductions; setprio around MFMA clusters.
// Micro-opt vs r12: P-writes issue inside the softmax loop (as each exp2
// result is ready) so the P write->read latency hides under the remaining
// DPP/exp2 chains instead of sitting exposed before PV.
__global__ __launch_bounds__(256, 2) void k_attn(const unsigned short* __restrict__ qb,
                                                 const unsigned short* __restrict__ kb,
                                                 const unsigned short* __restrict__ vtb,
                                                 const unsigned short* __restrict__ distb,
                                                 const float* __restrict__ mask,
                                                 float* __restrict__ out){
  __shared__ __align__(16) unsigned char sK[64 * 128];
  __shared__ __align__(16) unsigned char sV[64 * 128];      // V^T tile: [d][r]
  __shared__ __align__(16) unsigned char sSA[4][2624];      // 64 rows x 40 B + dump@2560; P overlays 0..2047
  __shared__ __align__(16) unsigned char sSB[4][2560];      // 64 rows x 40 B

  const float SCL  = 0.125f * 1.4426950408889634f;   // /sqrt(64) * log2(e)
  const float L2E  = 1.4426950408889634f;

  int bid = blockIdx.x;
  int wgid = (bid & 7) * 128 + (bid >> 3);           // bijective XCD swizzle (1024 % 8 == 0)
  int lt = wgid & 7, h = (wgid >> 3) & 15, b = wgid >> 7;
  int L0 = lt * 64;
  int bh = b * NH + h;
  int t = threadIdx.x, w = t >> 6, lane = t & 63, g = lane >> 4, lr = lane & 15;
  int lbase = 16 * w;
  unsigned char* mySA = sSA[w];
  unsigned char* mySB = sSB[w];
  unsigned char* myP  = mySA;                        // overlay: SA dead when P written
  const float* maskp = mask + b * SEQ;

  // Q fragments hoisted to registers (rows L0+16w+lr)
  const unsigned short* qrow = qb + (bh * SEQ + L0 + lbase + lr) * HD + 8 * g;
  bf16x8 aq0 = *(const bf16x8*)qrow;
  bf16x8 aq1 = *(const bf16x8*)(qrow + 32);

  // PE fragments: 5 tiles jt = w..w+4, 2 k-halves each
  bf16x8 pe[5][2];
#define LOAD_PE(JB) do {                                                     \
    const unsigned short* _pb = distb + ((JB) + 16*w + lr) * HD + 8*g;       \
    _Pragma("unroll")                                                        \
    for (int _j = 0; _j < 5; _j++){                                          \
      pe[_j][0] = *(const bf16x8*)(_pb + _j*16*HD);                          \
      pe[_j][1] = *(const bf16x8*)(_pb + _j*16*HD + 32); }                   \
  } while(0)

  // K/V reg-staging geometry: wave fills linear LDS rows [8w,8w+8) and
  // [8(w+4),...); lane covers chunk lc of row lrow, source inverse-swizzled.
  int lrow = lane >> 3, lc = lane & 7;
  int row0 = w * 8 + lrow,      row1 = (w + 4) * 8 + lrow;
  int cg0  = lc ^ (row0 & 7),   cg1  = lc ^ (row1 & 7);
  const unsigned short* kbase = kb  + bh * SEQ * HD;
  const unsigned short* vbase = vtb + bh * HD * SEQ;

  // prologue: issue tile-0 K/V loads into regs, PE for rt=0
  uint4 kst0 = *(const uint4*)(kbase + row0 * HD  + cg0 * 8);
  uint4 kst1 = *(const uint4*)(kbase + row1 * HD  + cg1 * 8);
  uint4 vst0 = *(const uint4*)(vbase + row0 * SEQ + cg0 * 8);
  uint4 vst1 = *(const uint4*)(vbase + row1 * SEQ + cg1 * 8);
  LOAD_PE(L0 + 448);

  f32x4 o[4] = {};
  float mrun[4], srun[4];
#pragma unroll
  for (int r = 0; r < 4; r++){ mrun[r] = -1e30f; srun[r] = 0.f; }

  for (int rt = 0; rt < 8; rt++){
    int R0 = rt * 64;

    // bar1: all waves done reading previous K/V tile
    bar_lds();

    // commit staged K/V tile to LDS (loads issued a full iteration ago)
    *(uint4*)(sK + w * 1024 + lane * 16)       = kst0;
    *(uint4*)(sK + (w + 4) * 1024 + lane * 16) = kst1;
    *(uint4*)(sV + w * 1024 + lane * 16)       = vst0;
    *(uint4*)(sV + (w + 4) * 1024 + lane * 16) = vst1;

    // issue next-tile K/V loads into regs
    if (rt < 7){
      const unsigned short* ks = kbase + (R0 + 64) * HD;
      const unsigned short* vs = vbase + (R0 + 64);
      kst0 = *(const uint4*)(ks + row0 * HD  + cg0 * 8);
      kst1 = *(const uint4*)(ks + row1 * HD  + cg1 * 8);
      vst0 = *(const uint4*)(vs + row0 * SEQ + cg0 * 8);
      vst1 = *(const uint4*)(vs + row1 * SEQ + cg1 * 8);
    }

    // mask values for this r-tile (column rr = 16f+lr)
    float mreg[4];
#pragma unroll
    for (int f = 0; f < 4; f++) mreg[f] = maskp[R0 + 16*f + lr];

    // bar2: staged writes visible to all waves
    bar_lds();

    __builtin_amdgcn_s_setprio(1);
    // merged QK + B-band per K-tile f (shares the two K fragment reads)
    f32x4 sc[4];
#pragma unroll
    for (int f = 0; f < 4; f++){
      bf16x8 k0 = *(const bf16x8*)(sK + swzc(16*f + lr, g));
      bf16x8 k1 = *(const bf16x8*)(sK + swzc(16*f + lr, 4 + g));
      f32x4 a = {};
      a = __builtin_amdgcn_mfma_f32_16x16x32_bf16(aq0, k0, a, 0, 0, 0);
      a = __builtin_amdgcn_mfma_f32_16x16x32_bf16(aq1, k1, a, 0, 0, 0);
      sc[f] = a;
      // B-band: i -> K rows 16f.., j -> PE tiles (3-f) and (4-f) relative to wave
      f32x4 b0 = {}, b1 = {};
      b0 = __builtin_amdgcn_mfma_f32_16x16x32_bf16(k0, pe[3 - f][0], b0, 0, 0, 0);
      b0 = __builtin_amdgcn_mfma_f32_16x16x32_bf16(k1, pe[3 - f][1], b0, 0, 0, 0);
      b1 = __builtin_amdgcn_mfma_f32_16x16x32_bf16(k0, pe[4 - f][0], b1, 0, 0, 0);
      b1 = __builtin_amdgcn_mfma_f32_16x16x32_bf16(k1, pe[4 - f][1], b1, 0, 0, 0);
#pragma unroll
      for (int reg = 0; reg < 4; reg++){
        int ss = 4*g + reg + lr;
        float v = (ss >= 15) ? b0[reg] : b1[reg];
        int row = 16*f + 4*g + reg;            // r_kv (block-local)
        int col = (ss + 1) & 15;               // l (wave-local) -- bijection
        *(unsigned short*)(mySB + row*40 + col*2) = f2bfr(v);
      }
    }

    // A-band: i -> q rows (wave-local l), j -> PE rows; store transposed [r_kv][l]
#pragma unroll
    for (int jt2 = 0; jt2 < 5; jt2++){
      f32x4 a = {};
      a = __builtin_amdgcn_mfma_f32_16x16x32_bf16(aq0, pe[jt2][0], a, 0, 0, 0);
      a = __builtin_amdgcn_mfma_f32_16x16x32_bf16(aq1, pe[jt2][1], a, 0, 0, 0);
#pragma unroll
      for (int reg = 0; reg < 4; reg++){
        int rloc = 63 + 4*g + reg - lr - 16*jt2;   // r_kv (block-local), may be OOR
        int addr = ((unsigned)rloc < 64u) ? (rloc*40 + (4*g + reg)*2) : 2560; // dump
        *(unsigned short*)(mySA + addr) = f2bfr(a[reg]);
      }
    }
    __builtin_amdgcn_s_setprio(0);

    // PE prefetch for next iteration (regs dead now; whole rest of iter to land)
    if (rt < 7) LOAD_PE(L0 + 448 - 64*(rt + 1));

    // score combine: qk + SA_T[rr][l] + SB[rr][l], scale, mask (exp2 domain)
#pragma unroll
    for (int f = 0; f < 4; f++){
      ushort4 sa = *(const ushort4*)(mySA + (16*f + lr)*40 + 8*g);
      ushort4 sb = *(const ushort4*)(mySB + (16*f + lr)*40 + 8*g);
      float madd = mreg[f] * L2E;
      sc[f][0] = (sc[f][0] + bf2f(sa.x) + bf2f(sb.x)) * SCL + madd;
      sc[f][1] = (sc[f][1] + bf2f(sa.y) + bf2f(sb.y)) * SCL + madd;
      sc[f][2] = (sc[f][2] + bf2f(sa.z) + bf2f(sb.z)) * SCL + madd;
      sc[f][3] = (sc[f][3] + bf2f(sa.w) + bf2f(sb.w)) * SCL + madd;
    }

    // online softmax (exp2 domain); DPP row reductions (VALU pipe).
    // P-writes issue as soon as each exp2 lands (after all SA/SB combine
    // reads -- same-wave in-order DS keeps the overlay safe), so the
    // write->read latency hides under the remaining reduction chains.
    float fac[4];
#pragma unroll
    for (int r = 0; r < 4; r++){
      float tm = fmaxf(fmaxf(sc[0][r], sc[1][r]), fmaxf(sc[2][r], sc[3][r]));
      tm = dpp_max16(tm);
      float mnew = fmaxf(mrun[r], tm);
      float fr = exp2f(mrun[r] - mnew);
      float ps = 0.f;
#pragma unroll
      for (int f = 0; f < 4; f++){
        float p = exp2f(sc[f][r] - mnew);
        ps += p;
        *(unsigned short*)(myP + swz2(4*g + r, 16*f + lr)) = f2bfr(p);
      }
      ps = dpp_sum16(ps);
      srun[r] = srun[r] * fr + ps;
      mrun[r] = mnew;
      fac[r]  = fr;
    }
#pragma unroll
    for (int df = 0; df < 4; df++)
#pragma unroll
      for (int r = 0; r < 4; r++) o[df][r] *= fac[r];

    // PV: O[16 l x 64 d] += P[16 l x 64 r] * V[64 r x 64 d]
    __builtin_amdgcn_s_setprio(1);
#pragma unroll
    for (int kk = 0; kk < 2; kk++){
      bf16x8 pf = *(const bf16x8*)(myP + swzc(lr, kk*4 + g));
#pragma unroll
      for (int df = 0; df < 4; df++){
        bf16x8 vf = *(const bf16x8*)(sV + swzc(16*df + lr, kk*4 + g));
        o[df] = __builtin_amdgcn_mfma_f32_16x16x32_bf16(pf, vf, o[df], 0, 0, 0);
      }
    }
    __builtin_amdgcn_s_setprio(0);
  }

  // epilogue: normalize and write out[b, l, h*64+d] (f32)
#pragma unroll
  for (int r = 0; r < 4; r++){
    float inv = 1.0f / srun[r];
#pragma unroll
    for (int df = 0; df < 4; df++){
      int l = L0 + lbase + 4*g + r;
      out[(b * SEQ + l) * EMB + h * HD + 16*df + lr] = o[df][r] * inv;
    }
  }
#undef LOAD_PE
}

extern "C" void kernel_launch(void* const* d_in, const int* in_sizes, int n_in,
                              void* d_out, int out_size, void* d_ws, size_t ws_size,
                              hipStream_t stream) {
  (void)in_sizes; (void)n_in; (void)out_size; (void)ws_size;
  const float* hid  = (const float*)d_in[0];
  const float* mask = (const float*)d_in[1];
  const float* Wq   = (const float*)d_in[2];
  const float* bq   = (const float*)d_in[3];
  const float* Wk   = (const float*)d_in[4];
  const float* bk   = (const float*)d_in[5];
  const float* Wv   = (const float*)d_in[6];
  const float* bv   = (const float*)d_in[7];
  const float* dist = (const float*)d_in[8];
  float* out = (float*)d_out;

  unsigned char* ws = (unsigned char*)d_ws;
  unsigned short* hidb  = (unsigned short*)ws;                    // 4096*1024 bf16 = 8 MB
  unsigned short* wqt   = hidb + 4096 * 1024;                     // 2 MB each
  unsigned short* wkt   = wqt  + 1024 * 1024;
  unsigned short* wvt   = wkt  + 1024 * 1024;
  unsigned short* distb = wvt  + 1024 * 1024;                     // 1024*64 bf16 (padded)
  unsigned short* qb    = distb + 1024 * 64;                      // [B,H,S,D] bf16, 8 MB
  unsigned short* kb    = qb + BATCH * NH * SEQ * HD;
  unsigned short* vtb   = kb + BATCH * NH * SEQ * HD;             // [B,H,D,S] bf16

  k_pre<<<7424, 256, 0, stream>>>(hid, hidb, dist, distb, Wq, Wk, Wv, wqt, wkt, wvt);
  k_gemm3<<<dim3(8, 32, 3), 256, 0, stream>>>(hidb, wqt, wkt, wvt, bq, bk, bv, qb, kb, vtb);
  k_attn<<<1024, 256, 0, stream>>>(qb, kb, vtb, distb, mask, out);
}